// Round 3
// baseline (723.488 us; speedup 1.0000x reference)
//
#include <hip/hip_runtime.h>

#define NUM_CLASSES 8

__device__ __forceinline__ int argmax8(const float4 a, const float4 b) {
    // strict > => first index wins ties (matches jnp.argmax)
    float m = a.x; int i = 0;
    if (a.y > m) { m = a.y; i = 1; }
    if (a.z > m) { m = a.z; i = 2; }
    if (a.w > m) { m = a.w; i = 3; }
    if (b.x > m) { m = b.x; i = 4; }
    if (b.y > m) { m = b.y; i = 5; }
    if (b.z > m) { m = b.z; i = 6; }
    if (b.w > m) { m = b.w; i = 7; }
    return i;
}

__device__ __forceinline__ unsigned int row_code(const float4* t4, const float4* p4, size_t r) {
    float4 ta = t4[2 * r], tb = t4[2 * r + 1];
    float4 pa = p4[2 * r], pb = p4[2 * r + 1];
    return (unsigned int)(argmax8(ta, tb) * NUM_CLASSES + argmax8(pa, pb));
}

// Pass 1: pure stream — read 512 MB, emit one code byte per row (packed u32).
// No LDS / atomics / shuffles in the hot loop.
__global__ __launch_bounds__(256) void codes_kernel(
    const float4* __restrict__ t4,
    const float4* __restrict__ p4,
    unsigned int* __restrict__ codes32,   // nrows/4 packed words
    int nrows)
{
    const size_t tid = (size_t)blockIdx.x * blockDim.x + threadIdx.x;
    const size_t nthreads = (size_t)gridDim.x * blockDim.x;
    const size_t ngroups = (size_t)nrows / 4;

    for (size_t g = tid; g < ngroups; g += nthreads) {
        const size_t r = g * 4;
        unsigned int c0 = row_code(t4, p4, r + 0);
        unsigned int c1 = row_code(t4, p4, r + 1);
        unsigned int c2 = row_code(t4, p4, r + 2);
        unsigned int c3 = row_code(t4, p4, r + 3);
        codes32[g] = c0 | (c1 << 8) | (c2 << 16) | (c3 << 24);
    }

    // tail rows (none for nrows = 2^23, but stay correct)
    const size_t tail_start = ngroups * 4;
    const size_t ntail = (size_t)nrows - tail_start;
    if (tid < ntail) {
        unsigned int c = row_code(t4, p4, tail_start + tid);
        ((unsigned char*)codes32)[tail_start + tid] = (unsigned char)c;
    }
}

// Pass 2: histogram 8.4 MB of codes. 8-way replicated LDS sub-histograms
// (replica = lane&7) to break same-address atomic serialization.
__global__ __launch_bounds__(256) void hist_kernel(
    const unsigned int* __restrict__ codes32,
    float* __restrict__ out,
    int nwords, int ntail_bytes)
{
    __shared__ unsigned int hist[64 * 8];
    for (int i = threadIdx.x; i < 64 * 8; i += 256) hist[i] = 0u;
    __syncthreads();

    const int rep = threadIdx.x & 7;
    const size_t tid = (size_t)blockIdx.x * blockDim.x + threadIdx.x;
    const size_t stride = (size_t)gridDim.x * blockDim.x;

    for (size_t i = tid; i < (size_t)nwords; i += stride) {
        unsigned int w = codes32[i];
        atomicAdd(&hist[((w)       & 63) * 8 + rep], 1u);
        atomicAdd(&hist[((w >> 8)  & 63) * 8 + rep], 1u);
        atomicAdd(&hist[((w >> 16) & 63) * 8 + rep], 1u);
        atomicAdd(&hist[((w >> 24) & 63) * 8 + rep], 1u);
    }
    if (blockIdx.x == 0 && (int)threadIdx.x < ntail_bytes) {
        unsigned char c = ((const unsigned char*)codes32)[(size_t)nwords * 4 + threadIdx.x];
        atomicAdd(&hist[(c & 63) * 8 + rep], 1u);
    }
    __syncthreads();

    if (threadIdx.x < 64) {
        unsigned int s = 0;
        #pragma unroll
        for (int r = 0; r < 8; ++r) s += hist[threadIdx.x * 8 + r];
        if (s) atomicAdd(&out[threadIdx.x], (float)s);
    }
}

// Fallback (ws too small): R1 single-pass kernel.
__global__ __launch_bounds__(256) void confusion_matrix_fallback(
    const float4* __restrict__ t4, const float4* __restrict__ p4,
    float* __restrict__ out, int nrows)
{
    __shared__ unsigned int hist[64];
    if (threadIdx.x < 64) hist[threadIdx.x] = 0u;
    __syncthreads();
    const size_t tid = (size_t)blockIdx.x * blockDim.x + threadIdx.x;
    const size_t stride = (size_t)gridDim.x * blockDim.x;
    for (size_t r = tid; r < (size_t)nrows; r += stride) {
        unsigned int c = row_code(t4, p4, r);
        atomicAdd(&hist[c], 1u);
    }
    __syncthreads();
    if (threadIdx.x < 64) {
        unsigned int v = hist[threadIdx.x];
        if (v) atomicAdd(&out[threadIdx.x], (float)v);
    }
}

extern "C" void kernel_launch(void* const* d_in, const int* in_sizes, int n_in,
                              void* d_out, int out_size, void* d_ws, size_t ws_size,
                              hipStream_t stream)
{
    const float4* y_true4 = (const float4*)d_in[0];
    const float4* y_pred4 = (const float4*)d_in[1];
    float* out = (float*)d_out;

    const int nrows = in_sizes[0] / NUM_CLASSES;   // 8388608

    hipMemsetAsync(out, 0, (size_t)out_size * sizeof(float), stream);

    if (ws_size >= (size_t)nrows) {
        unsigned int* codes32 = (unsigned int*)d_ws;
        const int block = 256;
        const int grid1 = 2048;   // 2^21 groups / 2^19 threads = 4 iters/thread
        codes_kernel<<<grid1, block, 0, stream>>>(y_true4, y_pred4, codes32, nrows);

        const int nwords = nrows / 4;
        const int ntail = nrows - nwords * 4;
        const int grid2 = 2048;
        hist_kernel<<<grid2, block, 0, stream>>>(codes32, out, nwords, ntail);
    } else {
        confusion_matrix_fallback<<<2048, 256, 0, stream>>>(y_true4, y_pred4, out, nrows);
    }
}